// Round 1
// baseline (2424.522 us; speedup 1.0000x reference)
//
#include <hip/hip_runtime.h>
#include <hip/hip_bf16.h>

#define N_NODES 100000
#define N_EDGES 1200000
#define HID 64
#define OUT_DIM 112
#define NLAYERS 7

static constexpr int SCAN_BLOCKS = (N_NODES + 255) / 256;  // 391

// ---------------- CSR build ----------------

__global__ __launch_bounds__(256) void k_hist(const int* __restrict__ dst, int* __restrict__ cnt) {
    int e = blockIdx.x * 256 + threadIdx.x;
    if (e < N_EDGES) atomicAdd(&cnt[dst[e]], 1);
}

__global__ __launch_bounds__(256) void k_scan_a(const int* __restrict__ cnt, int* __restrict__ inc,
                                                int* __restrict__ bsum) {
    __shared__ int lds[4];
    int i = blockIdx.x * 256 + threadIdx.x;
    int v = (i < N_NODES) ? cnt[i] : 0;
    int lane = threadIdx.x & 63, w = threadIdx.x >> 6;
    #pragma unroll
    for (int d = 1; d < 64; d <<= 1) {
        int u = __shfl_up(v, d, 64);
        if (lane >= d) v += u;
    }
    if (lane == 63) lds[w] = v;
    __syncthreads();
    int add = 0;
    for (int j = 0; j < w; ++j) add += lds[j];
    v += add;
    if (i < N_NODES) inc[i] = v;
    if (threadIdx.x == 255) bsum[blockIdx.x] = v;
}

__global__ __launch_bounds__(512) void k_scan_b(const int* __restrict__ bsum, int* __restrict__ boff, int nb) {
    __shared__ int lds[8];
    int t = threadIdx.x;
    int v0 = (t < nb) ? bsum[t] : 0;
    int v = v0;
    int lane = t & 63, w = t >> 6;
    #pragma unroll
    for (int d = 1; d < 64; d <<= 1) {
        int u = __shfl_up(v, d, 64);
        if (lane >= d) v += u;
    }
    if (lane == 63) lds[w] = v;
    __syncthreads();
    int add = 0;
    for (int j = 0; j < w; ++j) add += lds[j];
    boff[t] = v + add - v0;  // exclusive prefix
}

__global__ __launch_bounds__(256) void k_scan_c(const int* __restrict__ inc, const int* __restrict__ boff,
                                                int* __restrict__ rp) {
    int i = blockIdx.x * 256 + threadIdx.x;
    if (i < N_NODES) {
        rp[i + 1] = inc[i] + boff[blockIdx.x];
        if (i == 0) rp[0] = 0;
    }
}

__global__ __launch_bounds__(256) void k_scatter(const int* __restrict__ src, const int* __restrict__ dst,
                                                 int* __restrict__ nxt, int* __restrict__ ssrc,
                                                 int* __restrict__ eid) {
    int e = blockIdx.x * 256 + threadIdx.x;
    if (e < N_EDGES) {
        int pos = atomicAdd(&nxt[dst[e]], 1);
        ssrc[pos] = src[e];
        eid[pos] = e;
    }
}

// ---------------- encoders ----------------

// h[n][o] = b_node[o] + sum_k node_feats[n][k] * W_node[k][o]; one wave per node
__global__ __launch_bounds__(256) void k_node_enc(const float* __restrict__ nf, const float* __restrict__ Wn,
                                                  const float* __restrict__ bn, float* __restrict__ h) {
    __shared__ float Ws[128 * 64];
    int tid = threadIdx.x;
    for (int i = tid * 4; i < 128 * 64; i += 1024)
        *(float4*)&Ws[i] = *(const float4*)&Wn[i];
    __syncthreads();
    int lane = tid & 63, w = tid >> 6;
    float bv = bn[lane];
    for (int n0 = blockIdx.x * 4; n0 < N_NODES; n0 += gridDim.x * 4) {
        int n = n0 + w;
        float acc = bv;
        #pragma unroll
        for (int k = 0; k < 128; k += 4) {
            float4 a = *(const float4*)&nf[n * 128 + k];
            acc = fmaf(a.x, Ws[(k + 0) * 64 + lane], acc);
            acc = fmaf(a.y, Ws[(k + 1) * 64 + lane], acc);
            acc = fmaf(a.z, Ws[(k + 2) * 64 + lane], acc);
            acc = fmaf(a.w, Ws[(k + 3) * 64 + lane], acc);
        }
        h[n * 64 + lane] = acc;
    }
}

// eh_sorted[i][o] = bf16( b_edge[o] + sum_k edge_feats[eid[i]][k] * W_edge[k][o] )
__global__ __launch_bounds__(256) void k_edge_enc(const float* __restrict__ ef, const float* __restrict__ We,
                                                  const float* __restrict__ be, const int* __restrict__ eid,
                                                  __hip_bfloat16* __restrict__ eh) {
    int lane = threadIdx.x & 63, w = threadIdx.x >> 6;
    float wreg[8];
    #pragma unroll
    for (int k = 0; k < 8; ++k) wreg[k] = We[k * 64 + lane];
    float bv = be[lane];
    for (int i = blockIdx.x * 4 + w; i < N_EDGES; i += gridDim.x * 4) {
        int e = eid[i];
        float4 a = *(const float4*)&ef[e * 8];
        float4 b = *(const float4*)&ef[e * 8 + 4];
        float acc = bv;
        acc = fmaf(a.x, wreg[0], acc); acc = fmaf(a.y, wreg[1], acc);
        acc = fmaf(a.z, wreg[2], acc); acc = fmaf(a.w, wreg[3], acc);
        acc = fmaf(b.x, wreg[4], acc); acc = fmaf(b.y, wreg[5], acc);
        acc = fmaf(b.z, wreg[6], acc); acc = fmaf(b.w, wreg[7], acc);
        eh[(size_t)i * 64 + lane] = __float2bfloat16(acc);
    }
}

// ---------------- per-layer kernels ----------------

// x = relu(layernorm(h) * g + b); one wave per node, lane = feature
__global__ __launch_bounds__(256) void k_ln_relu(const float* __restrict__ h, float* __restrict__ x,
                                                 const float* __restrict__ g, const float* __restrict__ b) {
    int n = blockIdx.x * 4 + (threadIdx.x >> 6);
    int lane = threadIdx.x & 63;
    float v = h[n * 64 + lane];
    float s = v, ss = v * v;
    #pragma unroll
    for (int d = 1; d < 64; d <<= 1) {
        s += __shfl_xor(s, d, 64);
        ss += __shfl_xor(ss, d, 64);
    }
    float mu = s * (1.f / 64.f);
    float var = ss * (1.f / 64.f) - mu * mu;
    float xv = (v - mu) * rsqrtf(var + 1e-5f) * g[lane] + b[lane];
    x[n * 64 + lane] = fmaxf(xv, 0.f);
}

// online-softmax aggregation; one wave per dst node; xa = x + agg
__global__ __launch_bounds__(256) void k_agg(const float* __restrict__ x, const __hip_bfloat16* __restrict__ eh,
                                             const int* __restrict__ ssrc, const int* __restrict__ rp,
                                             const float* __restrict__ betas, int layer,
                                             float* __restrict__ xa) {
    int n = blockIdx.x * 4 + (threadIdx.x >> 6);
    int lane = threadIdx.x & 63;
    float beta = betas[layer];
    int r0 = rp[n], r1 = rp[n + 1];
    float M = -3.4e38f, S = 0.f, T = 0.f;
    for (int i = r0; i < r1; ++i) {
        int sidx = ssrc[i];
        float xv = x[sidx * 64 + lane];
        float ev = __bfloat162float(eh[(size_t)i * 64 + lane]);
        float m = fmaxf(xv + ev, 0.f) + 1e-7f;
        float l = m * beta;
        float nM = fmaxf(M, l);
        float p = __expf(l - nM);
        float sc = __expf(M - nM);
        S = S * sc + p;
        T = T * sc + m * p;
        M = nM;
    }
    float a = (r1 > r0) ? (T / S) : 0.f;
    xa[n * 64 + lane] = x[n * 64 + lane] + a;
}

// fused MLP: t1 = relu(LN(xa@W1 + b1)); h += t1@W2 + b2. 4 nodes per wave, weights in LDS.
__global__ __launch_bounds__(256) void k_mlp(const float* __restrict__ xa,
                                             const float* __restrict__ W1, const float* __restrict__ b1,
                                             const float* __restrict__ g1, const float* __restrict__ bt1,
                                             const float* __restrict__ W2, const float* __restrict__ b2,
                                             float* __restrict__ h) {
    __shared__ float W1s[64 * 128];
    __shared__ float W2s[128 * 64];
    __shared__ float xas[16 * 64];
    __shared__ float t1s[16 * 128];
    int tid = threadIdx.x;
    for (int i = tid * 4; i < 8192; i += 1024) {
        *(float4*)&W1s[i] = *(const float4*)&W1[i];
        *(float4*)&W2s[i] = *(const float4*)&W2[i];
    }
    int lane = tid & 63, w = tid >> 6;
    float2 b1v = ((const float2*)b1)[lane];
    float2 g1v = ((const float2*)g1)[lane];
    float2 bt1v = ((const float2*)bt1)[lane];
    float b2v = b2[lane];
    __syncthreads();
    for (int g = blockIdx.x; g < N_NODES / 16; g += gridDim.x) {
        int base = g * 16;
        __syncthreads();  // previous iteration's xas readers done
        *(float4*)&xas[tid * 4] = *(const float4*)&xa[base * 64 + tid * 4];
        __syncthreads();

        // GEMM1: outputs o = 2*lane, 2*lane+1 for 4 nodes
        float2 acc[4];
        #pragma unroll
        for (int j = 0; j < 4; ++j) acc[j] = b1v;
        const float2* W1s2 = (const float2*)W1s;
        #pragma unroll
        for (int k = 0; k < 64; k += 4) {
            float aq[4][4];
            #pragma unroll
            for (int j = 0; j < 4; ++j)
                *(float4*)&aq[j][0] = *(const float4*)&xas[(w * 4 + j) * 64 + k];
            #pragma unroll
            for (int kk = 0; kk < 4; ++kk) {
                float2 wv = W1s2[(k + kk) * 64 + lane];
                #pragma unroll
                for (int j = 0; j < 4; ++j) {
                    acc[j].x = fmaf(aq[j][kk], wv.x, acc[j].x);
                    acc[j].y = fmaf(aq[j][kk], wv.y, acc[j].y);
                }
            }
        }
        // LayerNorm(128) + relu per node, stage t1 row into LDS
        #pragma unroll
        for (int j = 0; j < 4; ++j) {
            float s = acc[j].x + acc[j].y;
            float ss = acc[j].x * acc[j].x + acc[j].y * acc[j].y;
            #pragma unroll
            for (int d = 1; d < 64; d <<= 1) {
                s += __shfl_xor(s, d, 64);
                ss += __shfl_xor(ss, d, 64);
            }
            float mu = s * (1.f / 128.f);
            float var = ss * (1.f / 128.f) - mu * mu;
            float rs = rsqrtf(var + 1e-5f);
            float t0 = fmaxf((acc[j].x - mu) * rs * g1v.x + bt1v.x, 0.f);
            float t1 = fmaxf((acc[j].y - mu) * rs * g1v.y + bt1v.y, 0.f);
            *(float2*)&t1s[(w * 4 + j) * 128 + 2 * lane] = make_float2(t0, t1);
        }
        // GEMM2: output o = lane for 4 nodes (t1s written/read by same wave)
        float acc2[4] = {b2v, b2v, b2v, b2v};
        #pragma unroll
        for (int k = 0; k < 128; k += 4) {
            float tq[4][4];
            #pragma unroll
            for (int j = 0; j < 4; ++j)
                *(float4*)&tq[j][0] = *(const float4*)&t1s[(w * 4 + j) * 128 + k];
            #pragma unroll
            for (int kk = 0; kk < 4; ++kk) {
                float wv = W2s[(k + kk) * 64 + lane];
                #pragma unroll
                for (int j = 0; j < 4; ++j) acc2[j] = fmaf(tq[j][kk], wv, acc2[j]);
            }
        }
        #pragma unroll
        for (int j = 0; j < 4; ++j) {
            int node = base + w * 4 + j;
            h[node * 64 + lane] += acc2[j];
        }
    }
}

// out[n][o] = b_out[o] + sum_k x[n][k] * W_out[k][o]; 2 nodes per 256-thread block iter
__global__ __launch_bounds__(256) void k_out(const float* __restrict__ x, const float* __restrict__ Wo,
                                             const float* __restrict__ bo, float* __restrict__ out) {
    __shared__ float Ws[64 * OUT_DIM];
    int tid = threadIdx.x;
    for (int i = tid; i < 64 * OUT_DIM; i += 256) Ws[i] = Wo[i];
    __syncthreads();
    int half = tid >> 7;
    int o = tid & 127;
    for (int g = blockIdx.x; g < N_NODES / 2; g += gridDim.x) {
        int n = g * 2 + half;
        if (o < OUT_DIM) {
            float acc = bo[o];
            #pragma unroll
            for (int k = 0; k < 64; k += 4) {
                float4 xv = *(const float4*)&x[n * 64 + k];
                acc = fmaf(xv.x, Ws[(k + 0) * OUT_DIM + o], acc);
                acc = fmaf(xv.y, Ws[(k + 1) * OUT_DIM + o], acc);
                acc = fmaf(xv.z, Ws[(k + 2) * OUT_DIM + o], acc);
                acc = fmaf(xv.w, Ws[(k + 3) * OUT_DIM + o], acc);
            }
            out[n * OUT_DIM + o] = acc;
        }
    }
}

// ---------------- launcher ----------------

extern "C" void kernel_launch(void* const* d_in, const int* in_sizes, int n_in,
                              void* d_out, int out_size, void* d_ws, size_t ws_size,
                              hipStream_t stream) {
    (void)in_sizes; (void)n_in; (void)out_size; (void)ws_size;
    const float* node_feats = (const float*)d_in[0];
    const float* edge_feats = (const float*)d_in[1];
    const int*   src        = (const int*)d_in[2];
    const int*   dst        = (const int*)d_in[3];
    const float* W_node     = (const float*)d_in[4];
    const float* b_node     = (const float*)d_in[5];
    const float* W_edge     = (const float*)d_in[6];
    const float* b_edge     = (const float*)d_in[7];
    const float* betas      = (const float*)d_in[8];
    const float* W1         = (const float*)d_in[9];
    const float* b1         = (const float*)d_in[10];
    const float* ln1_g      = (const float*)d_in[11];
    const float* ln1_b      = (const float*)d_in[12];
    const float* W2         = (const float*)d_in[13];
    const float* b2         = (const float*)d_in[14];
    const float* norm_g     = (const float*)d_in[15];
    const float* norm_b     = (const float*)d_in[16];
    const float* W_out      = (const float*)d_in[17];
    const float* b_out      = (const float*)d_in[18];
    float* out = (float*)d_out;

    char* p = (char*)d_ws;
    auto carve = [&](size_t bytes) {
        char* r = p;
        p += (bytes + 255) & ~(size_t)255;
        return r;
    };
    float* h   = (float*)carve((size_t)N_NODES * 64 * sizeof(float));
    float* x   = (float*)carve((size_t)N_NODES * 64 * sizeof(float));
    float* xa  = (float*)carve((size_t)N_NODES * 64 * sizeof(float));
    __hip_bfloat16* eh = (__hip_bfloat16*)carve((size_t)N_EDGES * 64 * sizeof(__hip_bfloat16));
    int* rp   = (int*)carve((size_t)(N_NODES + 1) * sizeof(int));
    int* nxt  = (int*)carve((size_t)N_NODES * sizeof(int));
    int* inc  = (int*)carve((size_t)N_NODES * sizeof(int));
    int* ssrc = (int*)carve((size_t)N_EDGES * sizeof(int));
    int* eid  = (int*)carve((size_t)N_EDGES * sizeof(int));
    int* bsum = (int*)carve(512 * sizeof(int));
    int* boff = (int*)carve(512 * sizeof(int));

    // CSR by dst
    hipMemsetAsync(nxt, 0, (size_t)N_NODES * sizeof(int), stream);
    k_hist<<<(N_EDGES + 255) / 256, 256, 0, stream>>>(dst, nxt);
    k_scan_a<<<SCAN_BLOCKS, 256, 0, stream>>>(nxt, inc, bsum);
    k_scan_b<<<1, 512, 0, stream>>>(bsum, boff, SCAN_BLOCKS);
    k_scan_c<<<SCAN_BLOCKS, 256, 0, stream>>>(inc, boff, rp);
    hipMemcpyAsync(nxt, rp, (size_t)N_NODES * sizeof(int), hipMemcpyDeviceToDevice, stream);
    k_scatter<<<(N_EDGES + 255) / 256, 256, 0, stream>>>(src, dst, nxt, ssrc, eid);

    // encoders
    k_node_enc<<<1024, 256, 0, stream>>>(node_feats, W_node, b_node, h);
    k_edge_enc<<<8192, 256, 0, stream>>>(edge_feats, W_edge, b_edge, eid, eh);

    // layers
    for (int i = 0; i < NLAYERS; ++i) {
        k_ln_relu<<<N_NODES / 4, 256, 0, stream>>>(h, x, norm_g + i * 64, norm_b + i * 64);
        k_agg<<<N_NODES / 4, 256, 0, stream>>>(x, eh, ssrc, rp, betas, i, xa);
        k_mlp<<<512, 256, 0, stream>>>(xa, W1 + i * 8192, b1 + i * 128,
                                       ln1_g + i * 128, ln1_b + i * 128,
                                       W2 + i * 8192, b2 + i * 64, h);
    }

    // final LN(norm[0]) + relu, then output linear
    k_ln_relu<<<N_NODES / 4, 256, 0, stream>>>(h, x, norm_g, norm_b);
    k_out<<<4096, 256, 0, stream>>>(x, W_out, b_out, out);
}

// Round 2
// 2018.158 us; speedup vs baseline: 1.2014x; 1.2014x over previous
//
#include <hip/hip_runtime.h>
#include <hip/hip_bf16.h>

#define N_NODES 100000
#define N_EDGES 1200000
#define HID 64
#define OUT_DIM 112
#define NLAYERS 7

static constexpr int SCAN_BLOCKS = (N_NODES + 255) / 256;  // 391

// ---------------- CSR build ----------------

__global__ __launch_bounds__(256) void k_hist(const int* __restrict__ dst, int* __restrict__ cnt) {
    int e = blockIdx.x * 256 + threadIdx.x;
    if (e < N_EDGES) atomicAdd(&cnt[dst[e]], 1);
}

__global__ __launch_bounds__(256) void k_scan_a(const int* __restrict__ cnt, int* __restrict__ inc,
                                                int* __restrict__ bsum) {
    __shared__ int lds[4];
    int i = blockIdx.x * 256 + threadIdx.x;
    int v = (i < N_NODES) ? cnt[i] : 0;
    int lane = threadIdx.x & 63, w = threadIdx.x >> 6;
    #pragma unroll
    for (int d = 1; d < 64; d <<= 1) {
        int u = __shfl_up(v, d, 64);
        if (lane >= d) v += u;
    }
    if (lane == 63) lds[w] = v;
    __syncthreads();
    int add = 0;
    for (int j = 0; j < w; ++j) add += lds[j];
    v += add;
    if (i < N_NODES) inc[i] = v;
    if (threadIdx.x == 255) bsum[blockIdx.x] = v;
}

__global__ __launch_bounds__(512) void k_scan_b(const int* __restrict__ bsum, int* __restrict__ boff, int nb) {
    __shared__ int lds[8];
    int t = threadIdx.x;
    int v0 = (t < nb) ? bsum[t] : 0;
    int v = v0;
    int lane = t & 63, w = t >> 6;
    #pragma unroll
    for (int d = 1; d < 64; d <<= 1) {
        int u = __shfl_up(v, d, 64);
        if (lane >= d) v += u;
    }
    if (lane == 63) lds[w] = v;
    __syncthreads();
    int add = 0;
    for (int j = 0; j < w; ++j) add += lds[j];
    boff[t] = v + add - v0;  // exclusive prefix
}

__global__ __launch_bounds__(256) void k_scan_c(const int* __restrict__ inc, const int* __restrict__ boff,
                                                int* __restrict__ rp) {
    int i = blockIdx.x * 256 + threadIdx.x;
    if (i < N_NODES) {
        rp[i + 1] = inc[i] + boff[blockIdx.x];
        if (i == 0) rp[0] = 0;
    }
}

__global__ __launch_bounds__(256) void k_scatter(const int* __restrict__ src, const int* __restrict__ dst,
                                                 int* __restrict__ nxt, int* __restrict__ ssrc,
                                                 int* __restrict__ eid) {
    int e = blockIdx.x * 256 + threadIdx.x;
    if (e < N_EDGES) {
        int pos = atomicAdd(&nxt[dst[e]], 1);
        ssrc[pos] = src[e];
        eid[pos] = e;
    }
}

// ---------------- encoders ----------------

__global__ __launch_bounds__(256) void k_node_enc(const float* __restrict__ nf, const float* __restrict__ Wn,
                                                  const float* __restrict__ bn, float* __restrict__ h) {
    __shared__ float Ws[128 * 64];
    int tid = threadIdx.x;
    for (int i = tid * 4; i < 128 * 64; i += 1024)
        *(float4*)&Ws[i] = *(const float4*)&Wn[i];
    __syncthreads();
    int lane = tid & 63, w = tid >> 6;
    float bv = bn[lane];
    for (int n0 = blockIdx.x * 4; n0 < N_NODES; n0 += gridDim.x * 4) {
        int n = n0 + w;
        float acc = bv;
        #pragma unroll
        for (int k = 0; k < 128; k += 4) {
            float4 a = *(const float4*)&nf[n * 128 + k];
            acc = fmaf(a.x, Ws[(k + 0) * 64 + lane], acc);
            acc = fmaf(a.y, Ws[(k + 1) * 64 + lane], acc);
            acc = fmaf(a.z, Ws[(k + 2) * 64 + lane], acc);
            acc = fmaf(a.w, Ws[(k + 3) * 64 + lane], acc);
        }
        h[n * 64 + lane] = acc;
    }
}

__global__ __launch_bounds__(256) void k_edge_enc(const float* __restrict__ ef, const float* __restrict__ We,
                                                  const float* __restrict__ be, const int* __restrict__ eid,
                                                  __hip_bfloat16* __restrict__ eh) {
    int lane = threadIdx.x & 63, w = threadIdx.x >> 6;
    float wreg[8];
    #pragma unroll
    for (int k = 0; k < 8; ++k) wreg[k] = We[k * 64 + lane];
    float bv = be[lane];
    for (int i = blockIdx.x * 4 + w; i < N_EDGES; i += gridDim.x * 4) {
        int e = eid[i];
        float4 a = *(const float4*)&ef[e * 8];
        float4 b = *(const float4*)&ef[e * 8 + 4];
        float acc = bv;
        acc = fmaf(a.x, wreg[0], acc); acc = fmaf(a.y, wreg[1], acc);
        acc = fmaf(a.z, wreg[2], acc); acc = fmaf(a.w, wreg[3], acc);
        acc = fmaf(b.x, wreg[4], acc); acc = fmaf(b.y, wreg[5], acc);
        acc = fmaf(b.z, wreg[6], acc); acc = fmaf(b.w, wreg[7], acc);
        eh[(size_t)i * 64 + lane] = __float2bfloat16(acc);
    }
}

// ---------------- per-layer kernels ----------------

// x = relu(layernorm(h) * g + b); one wave per node, lane = feature
__global__ __launch_bounds__(256) void k_ln_relu(const float* __restrict__ h, float* __restrict__ x,
                                                 const float* __restrict__ g, const float* __restrict__ b) {
    int n = blockIdx.x * 4 + (threadIdx.x >> 6);
    int lane = threadIdx.x & 63;
    float v = h[n * 64 + lane];
    float s = v, ss = v * v;
    #pragma unroll
    for (int d = 1; d < 64; d <<= 1) {
        s += __shfl_xor(s, d, 64);
        ss += __shfl_xor(ss, d, 64);
    }
    float mu = s * (1.f / 64.f);
    float var = ss * (1.f / 64.f) - mu * mu;
    float xv = (v - mu) * rsqrtf(var + 1e-5f) * g[lane] + b[lane];
    x[n * 64 + lane] = fmaxf(xv, 0.f);
}

// online-softmax aggregation, 4-edge unrolled; one wave per dst node; xa = x + agg
__global__ __launch_bounds__(256) void k_agg(const float* __restrict__ x, const __hip_bfloat16* __restrict__ eh,
                                             const int* __restrict__ ssrc, const int* __restrict__ rp,
                                             const float* __restrict__ betas, int layer,
                                             float* __restrict__ xa) {
    int n = blockIdx.x * 4 + (threadIdx.x >> 6);
    int lane = threadIdx.x & 63;
    float beta = betas[layer];
    int r0 = rp[n], r1 = rp[n + 1];
    float M = -3.4e38f, S = 0.f, T = 0.f;
    int i = r0;
    for (; i + 4 <= r1; i += 4) {
        int s0 = ssrc[i + 0], s1 = ssrc[i + 1], s2 = ssrc[i + 2], s3 = ssrc[i + 3];
        float xv0 = x[s0 * 64 + lane];
        float xv1 = x[s1 * 64 + lane];
        float xv2 = x[s2 * 64 + lane];
        float xv3 = x[s3 * 64 + lane];
        float ev0 = __bfloat162float(eh[(size_t)(i + 0) * 64 + lane]);
        float ev1 = __bfloat162float(eh[(size_t)(i + 1) * 64 + lane]);
        float ev2 = __bfloat162float(eh[(size_t)(i + 2) * 64 + lane]);
        float ev3 = __bfloat162float(eh[(size_t)(i + 3) * 64 + lane]);
        float m0 = fmaxf(xv0 + ev0, 0.f) + 1e-7f;
        float m1 = fmaxf(xv1 + ev1, 0.f) + 1e-7f;
        float m2 = fmaxf(xv2 + ev2, 0.f) + 1e-7f;
        float m3 = fmaxf(xv3 + ev3, 0.f) + 1e-7f;
        float l0 = m0 * beta, l1 = m1 * beta, l2 = m2 * beta, l3 = m3 * beta;
        float mx = fmaxf(fmaxf(l0, l1), fmaxf(l2, l3));
        float nM = fmaxf(M, mx);
        float sc = __expf(M - nM);
        float p0 = __expf(l0 - nM);
        float p1 = __expf(l1 - nM);
        float p2 = __expf(l2 - nM);
        float p3 = __expf(l3 - nM);
        S = S * sc + ((p0 + p1) + (p2 + p3));
        T = T * sc + ((m0 * p0 + m1 * p1) + (m2 * p2 + m3 * p3));
        M = nM;
    }
    for (; i < r1; ++i) {
        int sidx = ssrc[i];
        float xv = x[sidx * 64 + lane];
        float ev = __bfloat162float(eh[(size_t)i * 64 + lane]);
        float m = fmaxf(xv + ev, 0.f) + 1e-7f;
        float l = m * beta;
        float nM = fmaxf(M, l);
        float p = __expf(l - nM);
        float sc = __expf(M - nM);
        S = S * sc + p;
        T = T * sc + m * p;
        M = nM;
    }
    float a = (r1 > r0) ? (T / S) : 0.f;
    xa[n * 64 + lane] = x[n * 64 + lane] + a;
}

// fused MLP + next-layer LN/ReLU epilogue:
// t1 = relu(LN(xa@W1 + b1)); h += t1@W2 + b2; xout = relu(LN_next(h))
__global__ __launch_bounds__(256) void k_mlp(const float* __restrict__ xa,
                                             const float* __restrict__ W1, const float* __restrict__ b1,
                                             const float* __restrict__ g1, const float* __restrict__ bt1,
                                             const float* __restrict__ W2, const float* __restrict__ b2,
                                             const float* __restrict__ ng, const float* __restrict__ nb,
                                             float* __restrict__ h, float* __restrict__ xout) {
    __shared__ float W1s[64 * 128];
    __shared__ float W2s[128 * 64];
    __shared__ float xas[16 * 64];
    __shared__ float t1s[16 * 128];
    int tid = threadIdx.x;
    for (int i = tid * 4; i < 8192; i += 1024) {
        *(float4*)&W1s[i] = *(const float4*)&W1[i];
        *(float4*)&W2s[i] = *(const float4*)&W2[i];
    }
    int lane = tid & 63, w = tid >> 6;
    float2 b1v = ((const float2*)b1)[lane];
    float2 g1v = ((const float2*)g1)[lane];
    float2 bt1v = ((const float2*)bt1)[lane];
    float b2v = b2[lane];
    float ngv = ng[lane];
    float nbv = nb[lane];
    __syncthreads();
    for (int g = blockIdx.x; g < N_NODES / 16; g += gridDim.x) {
        int base = g * 16;
        __syncthreads();  // previous iteration's xas readers done
        *(float4*)&xas[tid * 4] = *(const float4*)&xa[base * 64 + tid * 4];
        __syncthreads();

        // GEMM1: outputs o = 2*lane, 2*lane+1 for 4 nodes
        float2 acc[4];
        #pragma unroll
        for (int j = 0; j < 4; ++j) acc[j] = b1v;
        const float2* W1s2 = (const float2*)W1s;
        #pragma unroll
        for (int k = 0; k < 64; k += 4) {
            float aq[4][4];
            #pragma unroll
            for (int j = 0; j < 4; ++j)
                *(float4*)&aq[j][0] = *(const float4*)&xas[(w * 4 + j) * 64 + k];
            #pragma unroll
            for (int kk = 0; kk < 4; ++kk) {
                float2 wv = W1s2[(k + kk) * 64 + lane];
                #pragma unroll
                for (int j = 0; j < 4; ++j) {
                    acc[j].x = fmaf(aq[j][kk], wv.x, acc[j].x);
                    acc[j].y = fmaf(aq[j][kk], wv.y, acc[j].y);
                }
            }
        }
        // LayerNorm(128) + relu per node, stage t1 row into LDS
        #pragma unroll
        for (int j = 0; j < 4; ++j) {
            float s = acc[j].x + acc[j].y;
            float ss = acc[j].x * acc[j].x + acc[j].y * acc[j].y;
            #pragma unroll
            for (int d = 1; d < 64; d <<= 1) {
                s += __shfl_xor(s, d, 64);
                ss += __shfl_xor(ss, d, 64);
            }
            float mu = s * (1.f / 128.f);
            float var = ss * (1.f / 128.f) - mu * mu;
            float rs = rsqrtf(var + 1e-5f);
            float t0 = fmaxf((acc[j].x - mu) * rs * g1v.x + bt1v.x, 0.f);
            float t1 = fmaxf((acc[j].y - mu) * rs * g1v.y + bt1v.y, 0.f);
            *(float2*)&t1s[(w * 4 + j) * 128 + 2 * lane] = make_float2(t0, t1);
        }
        // GEMM2: output o = lane for 4 nodes (t1s written/read by same wave)
        float acc2[4] = {b2v, b2v, b2v, b2v};
        #pragma unroll
        for (int k = 0; k < 128; k += 4) {
            float tq[4][4];
            #pragma unroll
            for (int j = 0; j < 4; ++j)
                *(float4*)&tq[j][0] = *(const float4*)&t1s[(w * 4 + j) * 128 + k];
            #pragma unroll
            for (int kk = 0; kk < 4; ++kk) {
                float wv = W2s[(k + kk) * 64 + lane];
                #pragma unroll
                for (int j = 0; j < 4; ++j) acc2[j] = fmaf(tq[j][kk], wv, acc2[j]);
            }
        }
        // residual + next-layer LN/ReLU epilogue
        #pragma unroll
        for (int j = 0; j < 4; ++j) {
            int node = base + w * 4 + j;
            float hv = h[node * 64 + lane] + acc2[j];
            h[node * 64 + lane] = hv;
            float s = hv, ss = hv * hv;
            #pragma unroll
            for (int d = 1; d < 64; d <<= 1) {
                s += __shfl_xor(s, d, 64);
                ss += __shfl_xor(ss, d, 64);
            }
            float mu = s * (1.f / 64.f);
            float var = ss * (1.f / 64.f) - mu * mu;
            float xv = (hv - mu) * rsqrtf(var + 1e-5f) * ngv + nbv;
            xout[node * 64 + lane] = fmaxf(xv, 0.f);
        }
    }
}

// out[n][o] = b_out[o] + sum_k x[n][k] * W_out[k][o]
__global__ __launch_bounds__(256) void k_out(const float* __restrict__ x, const float* __restrict__ Wo,
                                             const float* __restrict__ bo, float* __restrict__ out) {
    __shared__ float Ws[64 * OUT_DIM];
    int tid = threadIdx.x;
    for (int i = tid; i < 64 * OUT_DIM; i += 256) Ws[i] = Wo[i];
    __syncthreads();
    int half = tid >> 7;
    int o = tid & 127;
    for (int g = blockIdx.x; g < N_NODES / 2; g += gridDim.x) {
        int n = g * 2 + half;
        if (o < OUT_DIM) {
            float acc = bo[o];
            #pragma unroll
            for (int k = 0; k < 64; k += 4) {
                float4 xv = *(const float4*)&x[n * 64 + k];
                acc = fmaf(xv.x, Ws[(k + 0) * OUT_DIM + o], acc);
                acc = fmaf(xv.y, Ws[(k + 1) * OUT_DIM + o], acc);
                acc = fmaf(xv.z, Ws[(k + 2) * OUT_DIM + o], acc);
                acc = fmaf(xv.w, Ws[(k + 3) * OUT_DIM + o], acc);
            }
            out[n * OUT_DIM + o] = acc;
        }
    }
}

// ---------------- launcher ----------------

extern "C" void kernel_launch(void* const* d_in, const int* in_sizes, int n_in,
                              void* d_out, int out_size, void* d_ws, size_t ws_size,
                              hipStream_t stream) {
    (void)in_sizes; (void)n_in; (void)out_size; (void)ws_size;
    const float* node_feats = (const float*)d_in[0];
    const float* edge_feats = (const float*)d_in[1];
    const int*   src        = (const int*)d_in[2];
    const int*   dst        = (const int*)d_in[3];
    const float* W_node     = (const float*)d_in[4];
    const float* b_node     = (const float*)d_in[5];
    const float* W_edge     = (const float*)d_in[6];
    const float* b_edge     = (const float*)d_in[7];
    const float* betas      = (const float*)d_in[8];
    const float* W1         = (const float*)d_in[9];
    const float* b1         = (const float*)d_in[10];
    const float* ln1_g      = (const float*)d_in[11];
    const float* ln1_b      = (const float*)d_in[12];
    const float* W2         = (const float*)d_in[13];
    const float* b2         = (const float*)d_in[14];
    const float* norm_g     = (const float*)d_in[15];
    const float* norm_b     = (const float*)d_in[16];
    const float* W_out      = (const float*)d_in[17];
    const float* b_out      = (const float*)d_in[18];
    float* out = (float*)d_out;

    char* p = (char*)d_ws;
    auto carve = [&](size_t bytes) {
        char* r = p;
        p += (bytes + 255) & ~(size_t)255;
        return r;
    };
    float* h   = (float*)carve((size_t)N_NODES * 64 * sizeof(float));
    float* x   = (float*)carve((size_t)N_NODES * 64 * sizeof(float));
    float* xa  = (float*)carve((size_t)N_NODES * 64 * sizeof(float));
    __hip_bfloat16* eh = (__hip_bfloat16*)carve((size_t)N_EDGES * 64 * sizeof(__hip_bfloat16));
    int* rp   = (int*)carve((size_t)(N_NODES + 1) * sizeof(int));
    int* nxt  = (int*)carve((size_t)N_NODES * sizeof(int));
    int* inc  = (int*)carve((size_t)N_NODES * sizeof(int));
    int* ssrc = (int*)carve((size_t)N_EDGES * sizeof(int));
    int* eid  = (int*)carve((size_t)N_EDGES * sizeof(int));
    int* bsum = (int*)carve(512 * sizeof(int));
    int* boff = (int*)carve(512 * sizeof(int));

    // CSR by dst
    hipMemsetAsync(nxt, 0, (size_t)N_NODES * sizeof(int), stream);
    k_hist<<<(N_EDGES + 255) / 256, 256, 0, stream>>>(dst, nxt);
    k_scan_a<<<SCAN_BLOCKS, 256, 0, stream>>>(nxt, inc, bsum);
    k_scan_b<<<1, 512, 0, stream>>>(bsum, boff, SCAN_BLOCKS);
    k_scan_c<<<SCAN_BLOCKS, 256, 0, stream>>>(inc, boff, rp);
    hipMemcpyAsync(nxt, rp, (size_t)N_NODES * sizeof(int), hipMemcpyDeviceToDevice, stream);
    k_scatter<<<(N_EDGES + 255) / 256, 256, 0, stream>>>(src, dst, nxt, ssrc, eid);

    // encoders
    k_node_enc<<<1024, 256, 0, stream>>>(node_feats, W_node, b_node, h);
    k_edge_enc<<<8192, 256, 0, stream>>>(edge_feats, W_edge, b_edge, eid, eh);

    // first LN/ReLU (layer 0 input)
    k_ln_relu<<<N_NODES / 4, 256, 0, stream>>>(h, x, norm_g, norm_b);

    // layers; k_mlp epilogue produces x for layer i+1 (norm index (i+1)%7 -> final uses norm[0])
    for (int i = 0; i < NLAYERS; ++i) {
        int ni = (i + 1 < NLAYERS) ? (i + 1) : 0;
        k_agg<<<N_NODES / 4, 256, 0, stream>>>(x, eh, ssrc, rp, betas, i, xa);
        k_mlp<<<512, 256, 0, stream>>>(xa, W1 + i * 8192, b1 + i * 128,
                                       ln1_g + i * 128, ln1_b + i * 128,
                                       W2 + i * 8192, b2 + i * 64,
                                       norm_g + ni * 64, norm_b + ni * 64,
                                       h, x);
    }

    // output linear (x already = relu(LN_0(h)) from last mlp epilogue)
    k_out<<<4096, 256, 0, stream>>>(x, W_out, b_out, out);
}

// Round 3
// 1253.000 us; speedup vs baseline: 1.9350x; 1.6107x over previous
//
#include <hip/hip_runtime.h>
#include <hip/hip_bf16.h>

#define N_NODES 100000
#define N_PAD   100032   // 1563 * 64, padding for guard-free MFMA MLP
#define N_EDGES 1200000
#define HID 64
#define OUT_DIM 112
#define NLAYERS 7

static constexpr int SCAN_BLOCKS = (N_NODES + 255) / 256;  // 391

typedef __attribute__((ext_vector_type(8))) short short8v;
typedef __attribute__((ext_vector_type(4))) float f32x4;

__device__ __forceinline__ unsigned f2b(float f) {
    unsigned u = __builtin_bit_cast(unsigned, f);
    return (u + 0x7FFFu + ((u >> 16) & 1u)) >> 16;   // RNE bf16 bits in low 16
}

// ---------------- CSR build ----------------

__global__ __launch_bounds__(256) void k_hist(const int* __restrict__ dst, int* __restrict__ cnt) {
    int e = blockIdx.x * 256 + threadIdx.x;
    if (e < N_EDGES) atomicAdd(&cnt[dst[e]], 1);
}

__global__ __launch_bounds__(256) void k_scan_a(const int* __restrict__ cnt, int* __restrict__ inc,
                                                int* __restrict__ bsum) {
    __shared__ int lds[4];
    int i = blockIdx.x * 256 + threadIdx.x;
    int v = (i < N_NODES) ? cnt[i] : 0;
    int lane = threadIdx.x & 63, w = threadIdx.x >> 6;
    #pragma unroll
    for (int d = 1; d < 64; d <<= 1) {
        int u = __shfl_up(v, d, 64);
        if (lane >= d) v += u;
    }
    if (lane == 63) lds[w] = v;
    __syncthreads();
    int add = 0;
    for (int j = 0; j < w; ++j) add += lds[j];
    v += add;
    if (i < N_NODES) inc[i] = v;
    if (threadIdx.x == 255) bsum[blockIdx.x] = v;
}

__global__ __launch_bounds__(512) void k_scan_b(const int* __restrict__ bsum, int* __restrict__ boff, int nb) {
    __shared__ int lds[8];
    int t = threadIdx.x;
    int v0 = (t < nb) ? bsum[t] : 0;
    int v = v0;
    int lane = t & 63, w = t >> 6;
    #pragma unroll
    for (int d = 1; d < 64; d <<= 1) {
        int u = __shfl_up(v, d, 64);
        if (lane >= d) v += u;
    }
    if (lane == 63) lds[w] = v;
    __syncthreads();
    int add = 0;
    for (int j = 0; j < w; ++j) add += lds[j];
    boff[t] = v + add - v0;  // exclusive prefix
}

__global__ __launch_bounds__(256) void k_scan_c(const int* __restrict__ inc, const int* __restrict__ boff,
                                                int* __restrict__ rp) {
    int i = blockIdx.x * 256 + threadIdx.x;
    if (i < N_NODES) {
        rp[i + 1] = inc[i] + boff[blockIdx.x];
        if (i == 0) rp[0] = 0;
    }
}

__global__ __launch_bounds__(256) void k_scatter(const int* __restrict__ src, const int* __restrict__ dst,
                                                 int* __restrict__ nxt, int* __restrict__ ssrc,
                                                 int* __restrict__ pos) {
    int e = blockIdx.x * 256 + threadIdx.x;
    if (e < N_EDGES) {
        int p = atomicAdd(&nxt[dst[e]], 1);
        ssrc[p] = src[e];
        pos[e] = p;
    }
}

// ---------------- weight prep: transpose + bf16 ----------------
// W1T[l][o][k] (128x64), W2T[l][o][k] (64x128)
__global__ __launch_bounds__(256) void k_prep_w(const float* __restrict__ W1, const float* __restrict__ W2,
                                                short* __restrict__ W1T, short* __restrict__ W2T) {
    int t = blockIdx.x * 256 + threadIdx.x;
    if (t < NLAYERS * 8192) {
        int l = t >> 13, r = t & 8191;
        int o1 = r >> 6, k1 = r & 63;
        W1T[t] = (short)f2b(W1[l * 8192 + k1 * 128 + o1]);
        int o2 = r >> 7, k2 = r & 127;
        W2T[t] = (short)f2b(W2[l * 8192 + k2 * 64 + o2]);
    }
}

// ---------------- encoders ----------------

__global__ __launch_bounds__(256) void k_node_enc(const float* __restrict__ nf, const float* __restrict__ Wn,
                                                  const float* __restrict__ bn, float* __restrict__ h) {
    __shared__ float Ws[128 * 64];
    int tid = threadIdx.x;
    for (int i = tid * 4; i < 128 * 64; i += 1024)
        *(float4*)&Ws[i] = *(const float4*)&Wn[i];
    __syncthreads();
    int lane = tid & 63, w = tid >> 6;
    float bv = bn[lane];
    for (int n0 = blockIdx.x * 4; n0 < N_NODES; n0 += gridDim.x * 4) {
        int n = n0 + w;
        float acc = bv;
        #pragma unroll
        for (int k = 0; k < 128; k += 4) {
            float4 a = *(const float4*)&nf[n * 128 + k];
            acc = fmaf(a.x, Ws[(k + 0) * 64 + lane], acc);
            acc = fmaf(a.y, Ws[(k + 1) * 64 + lane], acc);
            acc = fmaf(a.z, Ws[(k + 2) * 64 + lane], acc);
            acc = fmaf(a.w, Ws[(k + 3) * 64 + lane], acc);
        }
        h[n * 64 + lane] = acc;
    }
}

// streaming read of ef in original order; scatter-write row to sorted slot pos[e]
__global__ __launch_bounds__(256) void k_edge_enc(const float* __restrict__ ef, const float* __restrict__ We,
                                                  const float* __restrict__ be, const int* __restrict__ pos,
                                                  __hip_bfloat16* __restrict__ eh) {
    int lane = threadIdx.x & 63, w = threadIdx.x >> 6;
    float wreg[8];
    #pragma unroll
    for (int k = 0; k < 8; ++k) wreg[k] = We[k * 64 + lane];
    float bv = be[lane];
    for (int e = blockIdx.x * 4 + w; e < N_EDGES; e += gridDim.x * 4) {
        float4 a = *(const float4*)&ef[e * 8];
        float4 b = *(const float4*)&ef[e * 8 + 4];
        int p = pos[e];
        float acc = bv;
        acc = fmaf(a.x, wreg[0], acc); acc = fmaf(a.y, wreg[1], acc);
        acc = fmaf(a.z, wreg[2], acc); acc = fmaf(a.w, wreg[3], acc);
        acc = fmaf(b.x, wreg[4], acc); acc = fmaf(b.y, wreg[5], acc);
        acc = fmaf(b.z, wreg[6], acc); acc = fmaf(b.w, wreg[7], acc);
        eh[(size_t)p * 64 + lane] = __float2bfloat16(acc);
    }
}

// ---------------- per-layer kernels ----------------

__global__ __launch_bounds__(256) void k_ln_relu(const float* __restrict__ h, float* __restrict__ x,
                                                 const float* __restrict__ g, const float* __restrict__ b) {
    int n = blockIdx.x * 4 + (threadIdx.x >> 6);
    int lane = threadIdx.x & 63;
    float v = h[n * 64 + lane];
    float s = v, ss = v * v;
    #pragma unroll
    for (int d = 1; d < 64; d <<= 1) {
        s += __shfl_xor(s, d, 64);
        ss += __shfl_xor(ss, d, 64);
    }
    float mu = s * (1.f / 64.f);
    float var = ss * (1.f / 64.f) - mu * mu;
    float xv = (v - mu) * rsqrtf(var + 1e-5f) * g[lane] + b[lane];
    x[n * 64 + lane] = fmaxf(xv, 0.f);
}

// online-softmax aggregation, 8-edge unrolled; one wave per dst node; xa = x + agg
__global__ __launch_bounds__(256) void k_agg(const float* __restrict__ x, const __hip_bfloat16* __restrict__ eh,
                                             const int* __restrict__ ssrc, const int* __restrict__ rp,
                                             const float* __restrict__ betas, int layer,
                                             float* __restrict__ xa) {
    int n = blockIdx.x * 4 + (threadIdx.x >> 6);
    int lane = threadIdx.x & 63;
    float beta = betas[layer];
    int r0 = rp[n], r1 = rp[n + 1];
    float M = -3.4e38f, S = 0.f, T = 0.f;
    int i = r0;
    // scalar head to 16B-align ssrc
    int ahead = (r0 + 3) & ~3;
    for (; i < ahead && i < r1; ++i) {
        int sidx = ssrc[i];
        float xv = x[sidx * 64 + lane];
        float ev = __bfloat162float(eh[(size_t)i * 64 + lane]);
        float m = fmaxf(xv + ev, 0.f) + 1e-7f;
        float l = m * beta;
        float nM = fmaxf(M, l);
        float p = __expf(l - nM);
        float sc = __expf(M - nM);
        S = S * sc + p;
        T = T * sc + m * p;
        M = nM;
    }
    for (; i + 8 <= r1; i += 8) {
        int4 sa = *(const int4*)&ssrc[i];
        int4 sb = *(const int4*)&ssrc[i + 4];
        float xv0 = x[sa.x * 64 + lane], xv1 = x[sa.y * 64 + lane];
        float xv2 = x[sa.z * 64 + lane], xv3 = x[sa.w * 64 + lane];
        float xv4 = x[sb.x * 64 + lane], xv5 = x[sb.y * 64 + lane];
        float xv6 = x[sb.z * 64 + lane], xv7 = x[sb.w * 64 + lane];
        float ev0 = __bfloat162float(eh[(size_t)(i + 0) * 64 + lane]);
        float ev1 = __bfloat162float(eh[(size_t)(i + 1) * 64 + lane]);
        float ev2 = __bfloat162float(eh[(size_t)(i + 2) * 64 + lane]);
        float ev3 = __bfloat162float(eh[(size_t)(i + 3) * 64 + lane]);
        float ev4 = __bfloat162float(eh[(size_t)(i + 4) * 64 + lane]);
        float ev5 = __bfloat162float(eh[(size_t)(i + 5) * 64 + lane]);
        float ev6 = __bfloat162float(eh[(size_t)(i + 6) * 64 + lane]);
        float ev7 = __bfloat162float(eh[(size_t)(i + 7) * 64 + lane]);
        float m0 = fmaxf(xv0 + ev0, 0.f) + 1e-7f, m1 = fmaxf(xv1 + ev1, 0.f) + 1e-7f;
        float m2 = fmaxf(xv2 + ev2, 0.f) + 1e-7f, m3 = fmaxf(xv3 + ev3, 0.f) + 1e-7f;
        float m4 = fmaxf(xv4 + ev4, 0.f) + 1e-7f, m5 = fmaxf(xv5 + ev5, 0.f) + 1e-7f;
        float m6 = fmaxf(xv6 + ev6, 0.f) + 1e-7f, m7 = fmaxf(xv7 + ev7, 0.f) + 1e-7f;
        float l0 = m0 * beta, l1 = m1 * beta, l2 = m2 * beta, l3 = m3 * beta;
        float l4 = m4 * beta, l5 = m5 * beta, l6 = m6 * beta, l7 = m7 * beta;
        float mx = fmaxf(fmaxf(fmaxf(l0, l1), fmaxf(l2, l3)), fmaxf(fmaxf(l4, l5), fmaxf(l6, l7)));
        float nM = fmaxf(M, mx);
        float sc = __expf(M - nM);
        float p0 = __expf(l0 - nM), p1 = __expf(l1 - nM), p2 = __expf(l2 - nM), p3 = __expf(l3 - nM);
        float p4 = __expf(l4 - nM), p5 = __expf(l5 - nM), p6 = __expf(l6 - nM), p7 = __expf(l7 - nM);
        S = S * sc + (((p0 + p1) + (p2 + p3)) + ((p4 + p5) + (p6 + p7)));
        T = T * sc + (((m0 * p0 + m1 * p1) + (m2 * p2 + m3 * p3)) +
                      ((m4 * p4 + m5 * p5) + (m6 * p6 + m7 * p7)));
        M = nM;
    }
    for (; i + 4 <= r1; i += 4) {
        int4 sa = *(const int4*)&ssrc[i];
        float xv0 = x[sa.x * 64 + lane], xv1 = x[sa.y * 64 + lane];
        float xv2 = x[sa.z * 64 + lane], xv3 = x[sa.w * 64 + lane];
        float ev0 = __bfloat162float(eh[(size_t)(i + 0) * 64 + lane]);
        float ev1 = __bfloat162float(eh[(size_t)(i + 1) * 64 + lane]);
        float ev2 = __bfloat162float(eh[(size_t)(i + 2) * 64 + lane]);
        float ev3 = __bfloat162float(eh[(size_t)(i + 3) * 64 + lane]);
        float m0 = fmaxf(xv0 + ev0, 0.f) + 1e-7f, m1 = fmaxf(xv1 + ev1, 0.f) + 1e-7f;
        float m2 = fmaxf(xv2 + ev2, 0.f) + 1e-7f, m3 = fmaxf(xv3 + ev3, 0.f) + 1e-7f;
        float l0 = m0 * beta, l1 = m1 * beta, l2 = m2 * beta, l3 = m3 * beta;
        float mx = fmaxf(fmaxf(l0, l1), fmaxf(l2, l3));
        float nM = fmaxf(M, mx);
        float sc = __expf(M - nM);
        float p0 = __expf(l0 - nM), p1 = __expf(l1 - nM), p2 = __expf(l2 - nM), p3 = __expf(l3 - nM);
        S = S * sc + ((p0 + p1) + (p2 + p3));
        T = T * sc + ((m0 * p0 + m1 * p1) + (m2 * p2 + m3 * p3));
        M = nM;
    }
    for (; i < r1; ++i) {
        int sidx = ssrc[i];
        float xv = x[sidx * 64 + lane];
        float ev = __bfloat162float(eh[(size_t)i * 64 + lane]);
        float m = fmaxf(xv + ev, 0.f) + 1e-7f;
        float l = m * beta;
        float nM = fmaxf(M, l);
        float p = __expf(l - nM);
        float sc = __expf(M - nM);
        S = S * sc + p;
        T = T * sc + m * p;
        M = nM;
    }
    float a = (r1 > r0) ? (T / S) : 0.f;
    xa[n * 64 + lane] = x[n * 64 + lane] + a;
}

// MFMA MLP: t1 = relu(LN(xa@W1 + b1)); h += t1@W2 + b2; xout = relu(LN_next(h))
// wave = 16 nodes; block = 4 waves = 64 nodes; grid = N_PAD/64 = 1563.
// C/D layout (verified): col = lane&15, row = (lane>>4)*4 + reg.
// A/B frag: row/col = lane&15, k = (lane>>4)*8 + j.
__global__ __launch_bounds__(256) void k_mlp_mfma(
    const float* __restrict__ xa, const short* __restrict__ W1T, const float* __restrict__ b1,
    const float* __restrict__ g1, const float* __restrict__ bt1,
    const short* __restrict__ W2T, const float* __restrict__ b2,
    const float* __restrict__ ng, const float* __restrict__ nb,
    float* __restrict__ h, float* __restrict__ xout) {
    __shared__ __align__(16) short W1s[8192];      // [o=128][k=64], XOR-swizzled
    __shared__ __align__(16) short W2s[8192];      // [o=64][k=128], XOR-swizzled
    __shared__ __align__(16) short xas[4][1024];   // per-wave [node=16][k=64]
    __shared__ __align__(16) short t1s[4][2048];   // per-wave [node=16][k=128]
    int tid = threadIdx.x;
    int lane = tid & 63, w = tid >> 6;

    // stage weights (already bf16, transposed) with XOR swizzle on 16B units
    {
        const int4* g1p = (const int4*)W1T;
        const int4* g2p = (const int4*)W2T;
        for (int u = tid; u < 1024; u += 256) {
            int byte = u * 16;
            int off1 = byte ^ ((((byte >> 7) & 7)) << 4);   // W1s rows = 128B
            *(int4*)((char*)W1s + off1) = g1p[u];
            int off2 = byte ^ ((((byte >> 8) & 7)) << 4);   // W2s rows = 256B
            *(int4*)((char*)W2s + off2) = g2p[u];
        }
    }
    // stage this wave's 16 nodes of xa -> bf16 LDS, swizzled
    int nbase = blockIdx.x * 64 + w * 16;
    #pragma unroll
    for (int it = 0; it < 4; ++it) {
        int idx = it * 256 + lane * 4;       // element index in [16][64]
        int node = idx >> 6, k0 = idx & 63;
        float4 v = *(const float4*)&xa[(size_t)(nbase + node) * 64 + k0];
        uint2 pk;
        pk.x = f2b(v.x) | (f2b(v.y) << 16);
        pk.y = f2b(v.z) | (f2b(v.w) << 16);
        int boff = (node * 128 + k0 * 2) ^ ((node & 7) << 4);
        *(uint2*)((char*)xas[w] + boff) = pk;
    }
    __syncthreads();

    int cg = lane >> 4;   // k-group / node-group
    int cl = lane & 15;   // col-in-tile, row for A-frags
    float b1v[8], g1v[8], t1bv[8];
    #pragma unroll
    for (int t = 0; t < 8; ++t) {
        b1v[t] = b1[t * 16 + cl]; g1v[t] = g1[t * 16 + cl]; t1bv[t] = bt1[t * 16 + cl];
    }
    // GEMM1: [16 nodes x 64k] @ [64k x 128o]
    f32x4 c1[8];
    #pragma unroll
    for (int t = 0; t < 8; ++t) c1[t] = (f32x4){b1v[t], b1v[t], b1v[t], b1v[t]};
    #pragma unroll
    for (int s = 0; s < 2; ++s) {
        int aoff = (cl * 128 + s * 64 + cg * 16) ^ ((cl & 7) << 4);
        short8v af = *(const short8v*)((char*)xas[w] + aoff);
        #pragma unroll
        for (int t = 0; t < 8; ++t) {
            int o = t * 16 + cl;
            int boff = (o * 128 + s * 64 + cg * 16) ^ ((o & 7) << 4);
            short8v bfv = *(const short8v*)((char*)W1s + boff);
            c1[t] = __builtin_amdgcn_mfma_f32_16x16x32_bf16(af, bfv, c1[t], 0, 0, 0);
        }
    }
    // LN(128) + relu, write t1 bf16 to swizzled LDS
    float sum[4] = {0, 0, 0, 0}, sq[4] = {0, 0, 0, 0};
    #pragma unroll
    for (int t = 0; t < 8; ++t)
        #pragma unroll
        for (int r = 0; r < 4; ++r) { sum[r] += c1[t][r]; sq[r] += c1[t][r] * c1[t][r]; }
    #pragma unroll
    for (int r = 0; r < 4; ++r)
        #pragma unroll
        for (int d = 1; d < 16; d <<= 1) {
            sum[r] += __shfl_xor(sum[r], d, 16);
            sq[r] += __shfl_xor(sq[r], d, 16);
        }
    float mu[4], rs[4];
    #pragma unroll
    for (int r = 0; r < 4; ++r) {
        mu[r] = sum[r] * (1.f / 128.f);
        float var = sq[r] * (1.f / 128.f) - mu[r] * mu[r];
        rs[r] = rsqrtf(var + 1e-5f);
    }
    #pragma unroll
    for (int t = 0; t < 8; ++t)
        #pragma unroll
        for (int r = 0; r < 4; ++r) {
            float v = fmaxf((c1[t][r] - mu[r]) * rs[r] * g1v[t] + t1bv[t], 0.f);
            int node = cg * 4 + r, o = t * 16 + cl;
            int boff = (node * 256 + o * 2) ^ ((node & 7) << 4);
            *(short*)((char*)t1s[w] + boff) = (short)f2b(v);
        }
    __syncthreads();
    // GEMM2: [16 nodes x 128k] @ [128k x 64o]
    float b2v[4], ngv[4], nbv[4];
    #pragma unroll
    for (int t = 0; t < 4; ++t) {
        b2v[t] = b2[t * 16 + cl]; ngv[t] = ng[t * 16 + cl]; nbv[t] = nb[t * 16 + cl];
    }
    f32x4 c2[4];
    #pragma unroll
    for (int t = 0; t < 4; ++t) c2[t] = (f32x4){b2v[t], b2v[t], b2v[t], b2v[t]};
    #pragma unroll
    for (int s = 0; s < 4; ++s) {
        int aoff = (cl * 256 + s * 64 + cg * 16) ^ ((cl & 7) << 4);
        short8v af = *(const short8v*)((char*)t1s[w] + aoff);
        #pragma unroll
        for (int t = 0; t < 4; ++t) {
            int o = t * 16 + cl;
            int boff = (o * 256 + s * 64 + cg * 16) ^ ((o & 7) << 4);
            short8v bfv = *(const short8v*)((char*)W2s + boff);
            c2[t] = __builtin_amdgcn_mfma_f32_16x16x32_bf16(af, bfv, c2[t], 0, 0, 0);
        }
    }
    // epilogue: h += y2; next-layer LN(64)+relu -> xout
    float hv[4][4];
    #pragma unroll
    for (int t = 0; t < 4; ++t)
        #pragma unroll
        for (int r = 0; r < 4; ++r) {
            int node = nbase + cg * 4 + r, o = t * 16 + cl;
            float v = h[(size_t)node * 64 + o] + c2[t][r];
            h[(size_t)node * 64 + o] = v;
            hv[t][r] = v;
        }
    float s2[4] = {0, 0, 0, 0}, q2[4] = {0, 0, 0, 0};
    #pragma unroll
    for (int t = 0; t < 4; ++t)
        #pragma unroll
        for (int r = 0; r < 4; ++r) { s2[r] += hv[t][r]; q2[r] += hv[t][r] * hv[t][r]; }
    #pragma unroll
    for (int r = 0; r < 4; ++r)
        #pragma unroll
        for (int d = 1; d < 16; d <<= 1) {
            s2[r] += __shfl_xor(s2[r], d, 16);
            q2[r] += __shfl_xor(q2[r], d, 16);
        }
    #pragma unroll
    for (int r = 0; r < 4; ++r) {
        float m2 = s2[r] * (1.f / 64.f);
        float var = q2[r] * (1.f / 64.f) - m2 * m2;
        float rv = rsqrtf(var + 1e-5f);
        #pragma unroll
        for (int t = 0; t < 4; ++t) {
            int node = nbase + cg * 4 + r, o = t * 16 + cl;
            float xv = (hv[t][r] - m2) * rv * ngv[t] + nbv[t];
            xout[(size_t)node * 64 + o] = fmaxf(xv, 0.f);
        }
    }
}

__global__ __launch_bounds__(256) void k_out(const float* __restrict__ x, const float* __restrict__ Wo,
                                             const float* __restrict__ bo, float* __restrict__ out) {
    __shared__ float Ws[64 * OUT_DIM];
    int tid = threadIdx.x;
    for (int i = tid; i < 64 * OUT_DIM; i += 256) Ws[i] = Wo[i];
    __syncthreads();
    int half = tid >> 7;
    int o = tid & 127;
    for (int g = blockIdx.x; g < N_NODES / 2; g += gridDim.x) {
        int n = g * 2 + half;
        if (o < OUT_DIM) {
            float acc = bo[o];
            #pragma unroll
            for (int k = 0; k < 64; k += 4) {
                float4 xv = *(const float4*)&x[n * 64 + k];
                acc = fmaf(xv.x, Ws[(k + 0) * OUT_DIM + o], acc);
                acc = fmaf(xv.y, Ws[(k + 1) * OUT_DIM + o], acc);
                acc = fmaf(xv.z, Ws[(k + 2) * OUT_DIM + o], acc);
                acc = fmaf(xv.w, Ws[(k + 3) * OUT_DIM + o], acc);
            }
            out[n * OUT_DIM + o] = acc;
        }
    }
}

// ---------------- launcher ----------------

extern "C" void kernel_launch(void* const* d_in, const int* in_sizes, int n_in,
                              void* d_out, int out_size, void* d_ws, size_t ws_size,
                              hipStream_t stream) {
    (void)in_sizes; (void)n_in; (void)out_size; (void)ws_size;
    const float* node_feats = (const float*)d_in[0];
    const float* edge_feats = (const float*)d_in[1];
    const int*   src        = (const int*)d_in[2];
    const int*   dst        = (const int*)d_in[3];
    const float* W_node     = (const float*)d_in[4];
    const float* b_node     = (const float*)d_in[5];
    const float* W_edge     = (const float*)d_in[6];
    const float* b_edge     = (const float*)d_in[7];
    const float* betas      = (const float*)d_in[8];
    const float* W1         = (const float*)d_in[9];
    const float* b1         = (const float*)d_in[10];
    const float* ln1_g      = (const float*)d_in[11];
    const float* ln1_b      = (const float*)d_in[12];
    const float* W2         = (const float*)d_in[13];
    const float* b2         = (const float*)d_in[14];
    const float* norm_g     = (const float*)d_in[15];
    const float* norm_b     = (const float*)d_in[16];
    const float* W_out      = (const float*)d_in[17];
    const float* b_out      = (const float*)d_in[18];
    float* out = (float*)d_out;

    char* p = (char*)d_ws;
    auto carve = [&](size_t bytes) {
        char* r = p;
        p += (bytes + 255) & ~(size_t)255;
        return r;
    };
    float* h   = (float*)carve((size_t)N_PAD * 64 * sizeof(float));
    float* x   = (float*)carve((size_t)N_PAD * 64 * sizeof(float));
    float* xa  = (float*)carve((size_t)N_PAD * 64 * sizeof(float));
    __hip_bfloat16* eh = (__hip_bfloat16*)carve((size_t)N_EDGES * 64 * sizeof(__hip_bfloat16));
    int* rp   = (int*)carve((size_t)(N_NODES + 1) * sizeof(int));
    int* nxt  = (int*)carve((size_t)N_NODES * sizeof(int));
    int* inc  = (int*)carve((size_t)N_NODES * sizeof(int));
    int* ssrc = (int*)carve((size_t)N_EDGES * sizeof(int));
    int* pos  = (int*)carve((size_t)N_EDGES * sizeof(int));
    int* bsum = (int*)carve(512 * sizeof(int));
    int* boff = (int*)carve(512 * sizeof(int));
    short* W1T = (short*)carve((size_t)NLAYERS * 8192 * sizeof(short));
    short* W2T = (short*)carve((size_t)NLAYERS * 8192 * sizeof(short));

    // CSR by dst (+ inverse permutation pos)
    hipMemsetAsync(nxt, 0, (size_t)N_NODES * sizeof(int), stream);
    k_hist<<<(N_EDGES + 255) / 256, 256, 0, stream>>>(dst, nxt);
    k_scan_a<<<SCAN_BLOCKS, 256, 0, stream>>>(nxt, inc, bsum);
    k_scan_b<<<1, 512, 0, stream>>>(bsum, boff, SCAN_BLOCKS);
    k_scan_c<<<SCAN_BLOCKS, 256, 0, stream>>>(inc, boff, rp);
    hipMemcpyAsync(nxt, rp, (size_t)N_NODES * sizeof(int), hipMemcpyDeviceToDevice, stream);
    k_scatter<<<(N_EDGES + 255) / 256, 256, 0, stream>>>(src, dst, nxt, ssrc, pos);

    // weight prep + encoders
    k_prep_w<<<(NLAYERS * 8192 + 255) / 256, 256, 0, stream>>>(W1, W2, W1T, W2T);
    k_node_enc<<<1024, 256, 0, stream>>>(node_feats, W_node, b_node, h);
    k_edge_enc<<<8192, 256, 0, stream>>>(edge_feats, W_edge, b_edge, pos, eh);

    // first LN/ReLU (layer 0 input)
    k_ln_relu<<<N_NODES / 4, 256, 0, stream>>>(h, x, norm_g, norm_b);

    // layers; k_mlp_mfma epilogue produces x for layer i+1 (final uses norm[0])
    for (int i = 0; i < NLAYERS; ++i) {
        int ni = (i + 1 < NLAYERS) ? (i + 1) : 0;
        k_agg<<<N_NODES / 4, 256, 0, stream>>>(x, eh, ssrc, rp, betas, i, xa);
        k_mlp_mfma<<<N_PAD / 64, 256, 0, stream>>>(xa, W1T + i * 8192, b1 + i * 128,
                                                   ln1_g + i * 128, ln1_b + i * 128,
                                                   W2T + i * 8192, b2 + i * 64,
                                                   norm_g + ni * 64, norm_b + ni * 64,
                                                   h, x);
    }

    // output linear (x already = relu(LN_0(h)) from last mlp epilogue)
    k_out<<<4096, 256, 0, stream>>>(x, W_out, b_out, out);
}

// Round 4
// 1154.368 us; speedup vs baseline: 2.1003x; 1.0854x over previous
//
#include <hip/hip_runtime.h>
#include <hip/hip_bf16.h>

#define N_NODES 100000
#define N_PAD   100032   // 1563 * 64, padding for guard-free MFMA MLP
#define N_EDGES 1200000
#define HID 64
#define OUT_DIM 112
#define NLAYERS 7

static constexpr int SCAN_BLOCKS = (N_NODES + 255) / 256;  // 391

typedef __attribute__((ext_vector_type(8))) short short8v;
typedef __attribute__((ext_vector_type(4))) float f32x4;
typedef unsigned int uint;

__device__ __forceinline__ unsigned f2b(float f) {
    unsigned u = __builtin_bit_cast(unsigned, f);
    return (u + 0x7FFFu + ((u >> 16) & 1u)) >> 16;   // RNE bf16 bits in low 16
}
__device__ __forceinline__ float blo(uint v) {
    return __builtin_bit_cast(float, (v & 0xFFFFu) << 16);
}
__device__ __forceinline__ float bhi(uint v) {
    return __builtin_bit_cast(float, v & 0xFFFF0000u);
}

// ---------------- CSR build ----------------

__global__ __launch_bounds__(256) void k_hist(const int* __restrict__ dst, int* __restrict__ cnt) {
    int e = blockIdx.x * 256 + threadIdx.x;
    if (e < N_EDGES) atomicAdd(&cnt[dst[e]], 1);
}

__global__ __launch_bounds__(256) void k_scan_a(const int* __restrict__ cnt, int* __restrict__ inc,
                                                int* __restrict__ bsum) {
    __shared__ int lds[4];
    int i = blockIdx.x * 256 + threadIdx.x;
    int v = (i < N_NODES) ? cnt[i] : 0;
    int lane = threadIdx.x & 63, w = threadIdx.x >> 6;
    #pragma unroll
    for (int d = 1; d < 64; d <<= 1) {
        int u = __shfl_up(v, d, 64);
        if (lane >= d) v += u;
    }
    if (lane == 63) lds[w] = v;
    __syncthreads();
    int add = 0;
    for (int j = 0; j < w; ++j) add += lds[j];
    v += add;
    if (i < N_NODES) inc[i] = v;
    if (threadIdx.x == 255) bsum[blockIdx.x] = v;
}

__global__ __launch_bounds__(512) void k_scan_b(const int* __restrict__ bsum, int* __restrict__ boff, int nb) {
    __shared__ int lds[8];
    int t = threadIdx.x;
    int v0 = (t < nb) ? bsum[t] : 0;
    int v = v0;
    int lane = t & 63, w = t >> 6;
    #pragma unroll
    for (int d = 1; d < 64; d <<= 1) {
        int u = __shfl_up(v, d, 64);
        if (lane >= d) v += u;
    }
    if (lane == 63) lds[w] = v;
    __syncthreads();
    int add = 0;
    for (int j = 0; j < w; ++j) add += lds[j];
    boff[t] = v + add - v0;  // exclusive prefix
}

__global__ __launch_bounds__(256) void k_scan_c(const int* __restrict__ inc, const int* __restrict__ boff,
                                                int* __restrict__ rp) {
    int i = blockIdx.x * 256 + threadIdx.x;
    if (i < N_NODES) {
        rp[i + 1] = inc[i] + boff[blockIdx.x];
        if (i == 0) rp[0] = 0;
    }
}

__global__ __launch_bounds__(256) void k_scatter(const int* __restrict__ src, const int* __restrict__ dst,
                                                 int* __restrict__ nxt, int* __restrict__ ssrc,
                                                 int* __restrict__ pos) {
    int e = blockIdx.x * 256 + threadIdx.x;
    if (e < N_EDGES) {
        int p = atomicAdd(&nxt[dst[e]], 1);
        ssrc[p] = src[e];
        pos[e] = p;
    }
}

// ---------------- weight prep: transpose + bf16 ----------------
__global__ __launch_bounds__(256) void k_prep_w(const float* __restrict__ W1, const float* __restrict__ W2,
                                                short* __restrict__ W1T, short* __restrict__ W2T) {
    int t = blockIdx.x * 256 + threadIdx.x;
    if (t < NLAYERS * 8192) {
        int l = t >> 13, r = t & 8191;
        int o1 = r >> 6, k1 = r & 63;
        W1T[t] = (short)f2b(W1[l * 8192 + k1 * 128 + o1]);
        int o2 = r >> 7, k2 = r & 127;
        W2T[t] = (short)f2b(W2[l * 8192 + k2 * 64 + o2]);
    }
}

// ---------------- encoders ----------------

// 8 nodes per wave, fused layer-0 LN/ReLU epilogue -> h, x, xb
__global__ __launch_bounds__(256) void k_node_enc(
    const float* __restrict__ nf, const float* __restrict__ Wn,
    const float* __restrict__ bn, const float* __restrict__ g,
    const float* __restrict__ b, float* __restrict__ h,
    float* __restrict__ x, unsigned short* __restrict__ xb) {
    __shared__ float Ws[128 * 64];
    int tid = threadIdx.x;
    for (int i = tid * 4; i < 128 * 64; i += 1024)
        *(float4*)&Ws[i] = *(const float4*)&Wn[i];
    __syncthreads();
    int lane = tid & 63, w = tid >> 6;
    float bv = bn[lane], gv = g[lane], bb = b[lane];
    for (int grp = blockIdx.x; grp < N_NODES / 32; grp += gridDim.x) {
        int base = grp * 32 + w * 8;
        float acc[8];
        #pragma unroll
        for (int j = 0; j < 8; ++j) acc[j] = bv;
        for (int k = 0; k < 128; k += 4) {
            float4 a[8];
            #pragma unroll
            for (int j = 0; j < 8; ++j) a[j] = *(const float4*)&nf[(size_t)(base + j) * 128 + k];
            float w0 = Ws[k * 64 + lane], w1 = Ws[(k + 1) * 64 + lane];
            float w2 = Ws[(k + 2) * 64 + lane], w3 = Ws[(k + 3) * 64 + lane];
            #pragma unroll
            for (int j = 0; j < 8; ++j) {
                acc[j] = fmaf(a[j].x, w0, acc[j]);
                acc[j] = fmaf(a[j].y, w1, acc[j]);
                acc[j] = fmaf(a[j].z, w2, acc[j]);
                acc[j] = fmaf(a[j].w, w3, acc[j]);
            }
        }
        #pragma unroll
        for (int j = 0; j < 8; ++j) {
            int node = base + j;
            float hv = acc[j];
            h[(size_t)node * 64 + lane] = hv;
            float s = hv, ss = hv * hv;
            #pragma unroll
            for (int d = 1; d < 64; d <<= 1) {
                s += __shfl_xor(s, d, 64);
                ss += __shfl_xor(ss, d, 64);
            }
            float mu = s * (1.f / 64.f);
            float var = ss * (1.f / 64.f) - mu * mu;
            float xv = fmaxf((hv - mu) * rsqrtf(var + 1e-5f) * gv + bb, 0.f);
            x[(size_t)node * 64 + lane] = xv;
            xb[(size_t)node * 64 + lane] = (unsigned short)f2b(xv);
        }
    }
}

// streaming read of ef in original order; scatter-write row to sorted slot pos[e]
__global__ __launch_bounds__(256) void k_edge_enc(const float* __restrict__ ef, const float* __restrict__ We,
                                                  const float* __restrict__ be, const int* __restrict__ pos,
                                                  __hip_bfloat16* __restrict__ eh) {
    int lane = threadIdx.x & 63, w = threadIdx.x >> 6;
    float wreg[8];
    #pragma unroll
    for (int k = 0; k < 8; ++k) wreg[k] = We[k * 64 + lane];
    float bv = be[lane];
    for (int e = blockIdx.x * 4 + w; e < N_EDGES; e += gridDim.x * 4) {
        float4 a = *(const float4*)&ef[e * 8];
        float4 b = *(const float4*)&ef[e * 8 + 4];
        int p = pos[e];
        float acc = bv;
        acc = fmaf(a.x, wreg[0], acc); acc = fmaf(a.y, wreg[1], acc);
        acc = fmaf(a.z, wreg[2], acc); acc = fmaf(a.w, wreg[3], acc);
        acc = fmaf(b.x, wreg[4], acc); acc = fmaf(b.y, wreg[5], acc);
        acc = fmaf(b.z, wreg[6], acc); acc = fmaf(b.w, wreg[7], acc);
        eh[(size_t)p * 64 + lane] = __float2bfloat16(acc);
    }
}

// ---------------- per-layer kernels ----------------

// online-softmax aggregation: wave = 1 dst node, 2 edge slots (lanes 0-31 / 32-63),
// each lane holds 2 features (bf16-pair loads). xa = x_f32 + agg.
__global__ __launch_bounds__(256) void k_agg(
    const float* __restrict__ x, const unsigned short* __restrict__ xb,
    const unsigned short* __restrict__ eh, const int* __restrict__ ssrc,
    const int* __restrict__ rp, const float* __restrict__ betas, int layer,
    float* __restrict__ xa) {
    int n = blockIdx.x * 4 + (threadIdx.x >> 6);
    int lane = threadIdx.x & 63;
    int half = lane >> 5;     // edge slot
    int fp = lane & 31;       // feature pair: feats 2fp, 2fp+1
    float beta = betas[layer];
    int r0 = rp[n], r1 = rp[n + 1];
    float Ma = -3.4e38f, Sa = 0.f, Ta = 0.f;
    float Mb = -3.4e38f, Sb = 0.f, Tb = 0.f;
    int i = r0 + half;
    for (; i + 6 < r1; i += 8) {   // this slot: edges i, i+2, i+4, i+6
        int s0 = ssrc[i], s1 = ssrc[i + 2], s2 = ssrc[i + 4], s3 = ssrc[i + 6];
        uint xv0 = *(const uint*)&xb[(size_t)s0 * 64 + 2 * fp];
        uint xv1 = *(const uint*)&xb[(size_t)s1 * 64 + 2 * fp];
        uint xv2 = *(const uint*)&xb[(size_t)s2 * 64 + 2 * fp];
        uint xv3 = *(const uint*)&xb[(size_t)s3 * 64 + 2 * fp];
        uint ev0 = *(const uint*)&eh[(size_t)(i + 0) * 64 + 2 * fp];
        uint ev1 = *(const uint*)&eh[(size_t)(i + 2) * 64 + 2 * fp];
        uint ev2 = *(const uint*)&eh[(size_t)(i + 4) * 64 + 2 * fp];
        uint ev3 = *(const uint*)&eh[(size_t)(i + 6) * 64 + 2 * fp];
        float m0a = fmaxf(blo(xv0) + blo(ev0), 0.f) + 1e-7f;
        float m1a = fmaxf(blo(xv1) + blo(ev1), 0.f) + 1e-7f;
        float m2a = fmaxf(blo(xv2) + blo(ev2), 0.f) + 1e-7f;
        float m3a = fmaxf(blo(xv3) + blo(ev3), 0.f) + 1e-7f;
        float m0b = fmaxf(bhi(xv0) + bhi(ev0), 0.f) + 1e-7f;
        float m1b = fmaxf(bhi(xv1) + bhi(ev1), 0.f) + 1e-7f;
        float m2b = fmaxf(bhi(xv2) + bhi(ev2), 0.f) + 1e-7f;
        float m3b = fmaxf(bhi(xv3) + bhi(ev3), 0.f) + 1e-7f;
        float l0a = m0a * beta, l1a = m1a * beta, l2a = m2a * beta, l3a = m3a * beta;
        float l0b = m0b * beta, l1b = m1b * beta, l2b = m2b * beta, l3b = m3b * beta;
        float mxa = fmaxf(fmaxf(l0a, l1a), fmaxf(l2a, l3a));
        float mxb = fmaxf(fmaxf(l0b, l1b), fmaxf(l2b, l3b));
        float nMa = fmaxf(Ma, mxa), nMb = fmaxf(Mb, mxb);
        float sca = __expf(Ma - nMa), scb = __expf(Mb - nMb);
        float p0a = __expf(l0a - nMa), p1a = __expf(l1a - nMa);
        float p2a = __expf(l2a - nMa), p3a = __expf(l3a - nMa);
        float p0b = __expf(l0b - nMb), p1b = __expf(l1b - nMb);
        float p2b = __expf(l2b - nMb), p3b = __expf(l3b - nMb);
        Sa = Sa * sca + ((p0a + p1a) + (p2a + p3a));
        Ta = Ta * sca + ((m0a * p0a + m1a * p1a) + (m2a * p2a + m3a * p3a));
        Sb = Sb * scb + ((p0b + p1b) + (p2b + p3b));
        Tb = Tb * scb + ((m0b * p0b + m1b * p1b) + (m2b * p2b + m3b * p3b));
        Ma = nMa; Mb = nMb;
    }
    for (; i < r1; i += 2) {
        int s0 = ssrc[i];
        uint xv0 = *(const uint*)&xb[(size_t)s0 * 64 + 2 * fp];
        uint ev0 = *(const uint*)&eh[(size_t)i * 64 + 2 * fp];
        float m0a = fmaxf(blo(xv0) + blo(ev0), 0.f) + 1e-7f;
        float m0b = fmaxf(bhi(xv0) + bhi(ev0), 0.f) + 1e-7f;
        float l0a = m0a * beta, l0b = m0b * beta;
        float nMa = fmaxf(Ma, l0a), nMb = fmaxf(Mb, l0b);
        float sca = __expf(Ma - nMa), scb = __expf(Mb - nMb);
        float p0a = __expf(l0a - nMa), p0b = __expf(l0b - nMb);
        Sa = Sa * sca + p0a;
        Ta = Ta * sca + m0a * p0a;
        Sb = Sb * scb + p0b;
        Tb = Tb * scb + m0b * p0b;
        Ma = nMa; Mb = nMb;
    }
    // merge the two edge slots (symmetric -> both halves get same result)
    {
        float Mo = __shfl_xor(Ma, 32, 64), So = __shfl_xor(Sa, 32, 64), To = __shfl_xor(Ta, 32, 64);
        float M = fmaxf(Ma, Mo);
        float ea = __expf(Ma - M), eo = __expf(Mo - M);
        Sa = Sa * ea + So * eo;
        Ta = Ta * ea + To * eo;
    }
    {
        float Mo = __shfl_xor(Mb, 32, 64), So = __shfl_xor(Sb, 32, 64), To = __shfl_xor(Tb, 32, 64);
        float M = fmaxf(Mb, Mo);
        float eb = __expf(Mb - M), eo = __expf(Mo - M);
        Sb = Sb * eb + So * eo;
        Tb = Tb * eb + To * eo;
    }
    if (half == 0) {
        float aa = (r1 > r0) ? (Ta / Sa) : 0.f;
        float ab = (r1 > r0) ? (Tb / Sb) : 0.f;
        float2 xv = *(const float2*)&x[(size_t)n * 64 + 2 * fp];
        *(float2*)&xa[(size_t)n * 64 + 2 * fp] = make_float2(xv.x + aa, xv.y + ab);
    }
}

// MFMA MLP: t1 = relu(LN(xa@W1 + b1)); h += t1@W2 + b2; xout/xbout = relu(LN_next(h))
__global__ __launch_bounds__(256) void k_mlp_mfma(
    const float* __restrict__ xa, const short* __restrict__ W1T, const float* __restrict__ b1,
    const float* __restrict__ g1, const float* __restrict__ bt1,
    const short* __restrict__ W2T, const float* __restrict__ b2,
    const float* __restrict__ ng, const float* __restrict__ nb,
    float* __restrict__ h, float* __restrict__ xout, unsigned short* __restrict__ xbout) {
    __shared__ __align__(16) short W1s[8192];      // [o=128][k=64], XOR-swizzled
    __shared__ __align__(16) short W2s[8192];      // [o=64][k=128], XOR-swizzled
    __shared__ __align__(16) short xas[4][1024];   // per-wave [node=16][k=64]
    __shared__ __align__(16) short t1s[4][2048];   // per-wave [node=16][k=128]
    int tid = threadIdx.x;
    int lane = tid & 63, w = tid >> 6;

    {
        const int4* g1p = (const int4*)W1T;
        const int4* g2p = (const int4*)W2T;
        for (int u = tid; u < 1024; u += 256) {
            int byte = u * 16;
            int off1 = byte ^ ((((byte >> 7) & 7)) << 4);   // W1s rows = 128B
            *(int4*)((char*)W1s + off1) = g1p[u];
            int off2 = byte ^ ((((byte >> 8) & 7)) << 4);   // W2s rows = 256B
            *(int4*)((char*)W2s + off2) = g2p[u];
        }
    }
    int nbase = blockIdx.x * 64 + w * 16;
    #pragma unroll
    for (int it = 0; it < 4; ++it) {
        int idx = it * 256 + lane * 4;
        int node = idx >> 6, k0 = idx & 63;
        float4 v = *(const float4*)&xa[(size_t)(nbase + node) * 64 + k0];
        uint2 pk;
        pk.x = f2b(v.x) | (f2b(v.y) << 16);
        pk.y = f2b(v.z) | (f2b(v.w) << 16);
        int boff = (node * 128 + k0 * 2) ^ ((node & 7) << 4);
        *(uint2*)((char*)xas[w] + boff) = pk;
    }
    __syncthreads();

    int cg = lane >> 4;
    int cl = lane & 15;
    float b1v[8], g1v[8], t1bv[8];
    #pragma unroll
    for (int t = 0; t < 8; ++t) {
        b1v[t] = b1[t * 16 + cl]; g1v[t] = g1[t * 16 + cl]; t1bv[t] = bt1[t * 16 + cl];
    }
    f32x4 c1[8];
    #pragma unroll
    for (int t = 0; t < 8; ++t) c1[t] = (f32x4){b1v[t], b1v[t], b1v[t], b1v[t]};
    #pragma unroll
    for (int s = 0; s < 2; ++s) {
        int aoff = (cl * 128 + s * 64 + cg * 16) ^ ((cl & 7) << 4);
        short8v af = *(const short8v*)((char*)xas[w] + aoff);
        #pragma unroll
        for (int t = 0; t < 8; ++t) {
            int o = t * 16 + cl;
            int boff = (o * 128 + s * 64 + cg * 16) ^ ((o & 7) << 4);
            short8v bfv = *(const short8v*)((char*)W1s + boff);
            c1[t] = __builtin_amdgcn_mfma_f32_16x16x32_bf16(af, bfv, c1[t], 0, 0, 0);
        }
    }
    float sum[4] = {0, 0, 0, 0}, sq[4] = {0, 0, 0, 0};
    #pragma unroll
    for (int t = 0; t < 8; ++t)
        #pragma unroll
        for (int r = 0; r < 4; ++r) { sum[r] += c1[t][r]; sq[r] += c1[t][r] * c1[t][r]; }
    #pragma unroll
    for (int r = 0; r < 4; ++r)
        #pragma unroll
        for (int d = 1; d < 16; d <<= 1) {
            sum[r] += __shfl_xor(sum[r], d, 16);
            sq[r] += __shfl_xor(sq[r], d, 16);
        }
    float mu[4], rs[4];
    #pragma unroll
    for (int r = 0; r < 4; ++r) {
        mu[r] = sum[r] * (1.f / 128.f);
        float var = sq[r] * (1.f / 128.f) - mu[r] * mu[r];
        rs[r] = rsqrtf(var + 1e-5f);
    }
    #pragma unroll
    for (int t = 0; t < 8; ++t)
        #pragma unroll
        for (int r = 0; r < 4; ++r) {
            float v = fmaxf((c1[t][r] - mu[r]) * rs[r] * g1v[t] + t1bv[t], 0.f);
            int node = cg * 4 + r, o = t * 16 + cl;
            int boff = (node * 256 + o * 2) ^ ((node & 7) << 4);
            *(short*)((char*)t1s[w] + boff) = (short)f2b(v);
        }
    __syncthreads();
    float b2v[4], ngv[4], nbv[4];
    #pragma unroll
    for (int t = 0; t < 4; ++t) {
        b2v[t] = b2[t * 16 + cl]; ngv[t] = ng[t * 16 + cl]; nbv[t] = nb[t * 16 + cl];
    }
    f32x4 c2[4];
    #pragma unroll
    for (int t = 0; t < 4; ++t) c2[t] = (f32x4){b2v[t], b2v[t], b2v[t], b2v[t]};
    #pragma unroll
    for (int s = 0; s < 4; ++s) {
        int aoff = (cl * 256 + s * 64 + cg * 16) ^ ((cl & 7) << 4);
        short8v af = *(const short8v*)((char*)t1s[w] + aoff);
        #pragma unroll
        for (int t = 0; t < 4; ++t) {
            int o = t * 16 + cl;
            int boff = (o * 256 + s * 64 + cg * 16) ^ ((o & 7) << 4);
            short8v bfv = *(const short8v*)((char*)W2s + boff);
            c2[t] = __builtin_amdgcn_mfma_f32_16x16x32_bf16(af, bfv, c2[t], 0, 0, 0);
        }
    }
    float hv[4][4];
    #pragma unroll
    for (int t = 0; t < 4; ++t)
        #pragma unroll
        for (int r = 0; r < 4; ++r) {
            int node = nbase + cg * 4 + r, o = t * 16 + cl;
            float v = h[(size_t)node * 64 + o] + c2[t][r];
            h[(size_t)node * 64 + o] = v;
            hv[t][r] = v;
        }
    float s2[4] = {0, 0, 0, 0}, q2[4] = {0, 0, 0, 0};
    #pragma unroll
    for (int t = 0; t < 4; ++t)
        #pragma unroll
        for (int r = 0; r < 4; ++r) { s2[r] += hv[t][r]; q2[r] += hv[t][r] * hv[t][r]; }
    #pragma unroll
    for (int r = 0; r < 4; ++r)
        #pragma unroll
        for (int d = 1; d < 16; d <<= 1) {
            s2[r] += __shfl_xor(s2[r], d, 16);
            q2[r] += __shfl_xor(q2[r], d, 16);
        }
    #pragma unroll
    for (int r = 0; r < 4; ++r) {
        float m2 = s2[r] * (1.f / 64.f);
        float var = q2[r] * (1.f / 64.f) - m2 * m2;
        float rv = rsqrtf(var + 1e-5f);
        #pragma unroll
        for (int t = 0; t < 4; ++t) {
            int node = nbase + cg * 4 + r, o = t * 16 + cl;
            float xv = fmaxf((hv[t][r] - m2) * rv * ngv[t] + nbv[t], 0.f);
            xout[(size_t)node * 64 + o] = xv;
            xbout[(size_t)node * 64 + o] = (unsigned short)f2b(xv);
        }
    }
}

__global__ __launch_bounds__(256) void k_out(const float* __restrict__ x, const float* __restrict__ Wo,
                                             const float* __restrict__ bo, float* __restrict__ out) {
    __shared__ float Ws[64 * OUT_DIM];
    int tid = threadIdx.x;
    for (int i = tid; i < 64 * OUT_DIM; i += 256) Ws[i] = Wo[i];
    __syncthreads();
    int half = tid >> 7;
    int o = tid & 127;
    for (int g = blockIdx.x; g < N_NODES / 2; g += gridDim.x) {
        int n = g * 2 + half;
        if (o < OUT_DIM) {
            float acc = bo[o];
            #pragma unroll
            for (int k = 0; k < 64; k += 4) {
                float4 xv = *(const float4*)&x[n * 64 + k];
                acc = fmaf(xv.x, Ws[(k + 0) * OUT_DIM + o], acc);
                acc = fmaf(xv.y, Ws[(k + 1) * OUT_DIM + o], acc);
                acc = fmaf(xv.z, Ws[(k + 2) * OUT_DIM + o], acc);
                acc = fmaf(xv.w, Ws[(k + 3) * OUT_DIM + o], acc);
            }
            out[n * OUT_DIM + o] = acc;
        }
    }
}

// ---------------- launcher ----------------

extern "C" void kernel_launch(void* const* d_in, const int* in_sizes, int n_in,
                              void* d_out, int out_size, void* d_ws, size_t ws_size,
                              hipStream_t stream) {
    (void)in_sizes; (void)n_in; (void)out_size; (void)ws_size;
    const float* node_feats = (const float*)d_in[0];
    const float* edge_feats = (const float*)d_in[1];
    const int*   src        = (const int*)d_in[2];
    const int*   dst        = (const int*)d_in[3];
    const float* W_node     = (const float*)d_in[4];
    const float* b_node     = (const float*)d_in[5];
    const float* W_edge     = (const float*)d_in[6];
    const float* b_edge     = (const float*)d_in[7];
    const float* betas      = (const float*)d_in[8];
    const float* W1         = (const float*)d_in[9];
    const float* b1         = (const float*)d_in[10];
    const float* ln1_g      = (const float*)d_in[11];
    const float* ln1_b      = (const float*)d_in[12];
    const float* W2         = (const float*)d_in[13];
    const float* b2         = (const float*)d_in[14];
    const float* norm_g     = (const float*)d_in[15];
    const float* norm_b     = (const float*)d_in[16];
    const float* W_out      = (const float*)d_in[17];
    const float* b_out      = (const float*)d_in[18];
    float* out = (float*)d_out;

    char* p = (char*)d_ws;
    auto carve = [&](size_t bytes) {
        char* r = p;
        p += (bytes + 255) & ~(size_t)255;
        return r;
    };
    float* h   = (float*)carve((size_t)N_PAD * 64 * sizeof(float));
    float* x   = (float*)carve((size_t)N_PAD * 64 * sizeof(float));
    float* xa  = (float*)carve((size_t)N_PAD * 64 * sizeof(float));
    unsigned short* xb = (unsigned short*)carve((size_t)N_PAD * 64 * sizeof(short));
    __hip_bfloat16* eh = (__hip_bfloat16*)carve((size_t)N_EDGES * 64 * sizeof(__hip_bfloat16));
    int* rp   = (int*)carve((size_t)(N_NODES + 1) * sizeof(int));
    int* nxt  = (int*)carve((size_t)N_NODES * sizeof(int));
    int* inc  = (int*)carve((size_t)N_NODES * sizeof(int));
    int* ssrc = (int*)carve((size_t)N_EDGES * sizeof(int));
    int* pos  = (int*)carve((size_t)N_EDGES * sizeof(int));
    int* bsum = (int*)carve(512 * sizeof(int));
    int* boff = (int*)carve(512 * sizeof(int));
    short* W1T = (short*)carve((size_t)NLAYERS * 8192 * sizeof(short));
    short* W2T = (short*)carve((size_t)NLAYERS * 8192 * sizeof(short));

    // CSR by dst (+ inverse permutation pos)
    hipMemsetAsync(nxt, 0, (size_t)N_NODES * sizeof(int), stream);
    k_hist<<<(N_EDGES + 255) / 256, 256, 0, stream>>>(dst, nxt);
    k_scan_a<<<SCAN_BLOCKS, 256, 0, stream>>>(nxt, inc, bsum);
    k_scan_b<<<1, 512, 0, stream>>>(bsum, boff, SCAN_BLOCKS);
    k_scan_c<<<SCAN_BLOCKS, 256, 0, stream>>>(inc, boff, rp);
    hipMemcpyAsync(nxt, rp, (size_t)N_NODES * sizeof(int), hipMemcpyDeviceToDevice, stream);
    k_scatter<<<(N_EDGES + 255) / 256, 256, 0, stream>>>(src, dst, nxt, ssrc, pos);

    // weight prep + encoders (node_enc fuses layer-0 LN/ReLU)
    k_prep_w<<<(NLAYERS * 8192 + 255) / 256, 256, 0, stream>>>(W1, W2, W1T, W2T);
    k_node_enc<<<1563, 256, 0, stream>>>(node_feats, W_node, b_node, norm_g, norm_b, h, x, xb);
    k_edge_enc<<<8192, 256, 0, stream>>>(edge_feats, W_edge, b_edge, pos, eh);

    // layers; k_mlp_mfma epilogue produces x/xb for layer i+1 (final uses norm[0])
    for (int i = 0; i < NLAYERS; ++i) {
        int ni = (i + 1 < NLAYERS) ? (i + 1) : 0;
        k_agg<<<N_NODES / 4, 256, 0, stream>>>(x, xb, (const unsigned short*)eh, ssrc, rp, betas, i, xa);
        k_mlp_mfma<<<N_PAD / 64, 256, 0, stream>>>(xa, W1T + i * 8192, b1 + i * 128,
                                                   ln1_g + i * 128, ln1_b + i * 128,
                                                   W2T + i * 8192, b2 + i * 64,
                                                   norm_g + ni * 64, norm_b + ni * 64,
                                                   h, x, xb);
    }

    // output linear (x already = relu(LN_0(h)) from last mlp epilogue)
    k_out<<<4096, 256, 0, stream>>>(x, W_out, b_out, out);
}